// Round 5
// baseline (801.505 us; speedup 1.0000x reference)
//
#include <hip/hip_runtime.h>
#include <stdint.h>

// Problem constants (static shapes from the reference)
constexpr int Bq = 2;
constexpr int Qn = 300;
constexpr int Cn = 80;
constexpr int Kn = 300;
constexpr int NFLAT = Qn * Cn;   // 24000
constexpr int MHs = 128;
constexpr int MWs = 128;
constexpr int THs = 320;
constexpr int TWs = 320;

// Output layout (flat concatenation in reference return order, all as float)
constexpr int OFF_SCORES = 0;                         // [B,K]     600
constexpr int OFF_LABELS = Bq * Kn;                   // [B,K]     600
constexpr int OFF_BOXES  = 2 * Bq * Kn;               // [B,K,4]   2400
constexpr int OFF_MASKS  = 2 * Bq * Kn + Bq * Kn * 4; // [B,K,320,320]

constexpr int TPB = 1024;
constexpr int EPT = (NFLAT + TPB - 1) / TPB;          // 24 elements/thread

typedef float vf4 __attribute__((ext_vector_type(4)));  // native vec (NT-store OK)

// ---------------------------------------------------------------------------
// Kernel A v4: per-batch top-K. Register-resident sigmoid bits; one 14-bit
// histogram (16384 packed-u16 bins); suffix scan locates rank-K bin; collect
// candidates; padded bitonic-1024 sort (deterministic ~4 us) replaces the
// runtime-length rank-by-count loop. Exact jax.lax.top_k order:
// key = (sigmoid_bits<<32) | (~flat_idx)  (unique keys, ties -> lowest idx).
// ---------------------------------------------------------------------------
__global__ __launch_bounds__(TPB) void topk_kernel(
    const float* __restrict__ logits,   // [B,Q,C]
    const float* __restrict__ boxes,    // [B,Q,4] cxcywh
    const float* __restrict__ osz,      // [B,2] (w,h)
    float* __restrict__ out,
    int* __restrict__ qidx_ws)          // [B,K]
{
    const int b   = blockIdx.x;
    const int tid = threadIdx.x;
    const float* lg = logits + (size_t)b * NFLAT;

    uint32_t bits[EPT];
    #pragma unroll
    for (int j = 0; j < EPT; ++j) {
        int idx = j * TPB + tid;
        bool valid = (idx < NFLAT);
        float x = valid ? lg[idx] : 0.0f;
        float s = 1.0f / (1.0f + expf(-x));
        bits[j] = valid ? __float_as_uint(s) : 0u;
    }

    __shared__ uint32_t bins[8192];        // 16384 u16 counts, packed
    __shared__ int scanA[1024], scanB[1024];
    __shared__ unsigned long long sk[1024];
    __shared__ int s_cnt, s_seg, s_B;

    {
        uint4* b4 = (uint4*)bins;
        for (int i = tid; i < 8192 / 4; i += TPB) b4[i] = make_uint4(0, 0, 0, 0);
    }
    sk[tid] = 0ull;                        // pad for bitonic
    if (tid == 0) s_cnt = 0;
    __syncthreads();

    // Histogram of top-14 bits
    #pragma unroll
    for (int j = 0; j < EPT; ++j) {
        int idx = j * TPB + tid;
        if (idx < NFLAT) {
            uint32_t bin = bits[j] >> 18;
            atomicAdd(&bins[bin >> 1], 1u << ((bin & 1u) * 16));
        }
    }
    __syncthreads();

    // Per-thread segment sum (16 bins = 8 packed u32s)
    int sum = 0;
    #pragma unroll
    for (int k = 0; k < 8; ++k) {
        uint32_t v = bins[tid * 8 + k];
        sum += (int)(v & 0xFFFFu) + (int)(v >> 16);
    }
    scanA[tid] = sum;
    __syncthreads();

    // Hillis-Steele suffix scan
    int* src = scanA;
    int* dst = scanB;
    for (int d = 1; d < 1024; d <<= 1) {
        int v = src[tid] + ((tid + d < 1024) ? src[tid + d] : 0);
        dst[tid] = v;
        __syncthreads();
        int* t = src; src = dst; dst = t;
    }
    // src[t] = count of elements with bin >= 16*t

    int sfx  = src[tid];
    int sfx1 = (tid < 1023) ? src[tid + 1] : 0;
    if (sfx >= Kn && sfx1 < Kn) s_seg = tid;       // unique
    __syncthreads();

    if (tid == 0) {
        int t = s_seg;
        int cumAbove = (t < 1023) ? src[t + 1] : 0;
        int B = t * 16;
        for (int i = 15; i >= 0; --i) {
            int bin = t * 16 + i;
            int c = (int)((bins[bin >> 1] >> ((bin & 1) * 16)) & 0xFFFFu);
            if (cumAbove + c >= Kn) { B = bin; break; }
            cumAbove += c;
        }
        s_B = B;
    }
    __syncthreads();

    // Collect candidates (bin >= threshold bin); n in [300, ~700]
    const uint32_t Bv = (uint32_t)s_B;
    #pragma unroll
    for (int j = 0; j < EPT; ++j) {
        int idx = j * TPB + tid;
        if (idx < NFLAT && (bits[j] >> 18) >= Bv) {
            int p = atomicAdd(&s_cnt, 1);
            if (p < 1024) {
                sk[p] = ((uint64_t)bits[j] << 32)
                      | (uint64_t)(0xFFFFFFFFu - (uint32_t)idx);
            }
        }
    }
    __syncthreads();

    // Bitonic sort 1024 descending (zeros pad to the end)
    for (int k2 = 2; k2 <= 1024; k2 <<= 1) {
        for (int j = k2 >> 1; j > 0; j >>= 1) {
            int ixj = tid ^ j;
            if (ixj > tid) {
                unsigned long long a = sk[tid], c2 = sk[ixj];
                bool up = ((tid & k2) == 0);           // descending overall
                if (up ? (a < c2) : (a > c2)) { sk[tid] = c2; sk[ixj] = a; }
            }
            __syncthreads();
        }
    }

    if (tid < Kn) {
        unsigned long long my = sk[tid];
        uint32_t idx = 0xFFFFFFFFu - (uint32_t)(my & 0xFFFFFFFFull);
        float score  = __uint_as_float((uint32_t)(my >> 32));
        int label = (int)(idx % (uint32_t)Cn);
        int q     = (int)(idx / (uint32_t)Cn);

        out[OFF_SCORES + b * Kn + tid] = score;
        out[OFF_LABELS + b * Kn + tid] = (float)label;

        const float sw = osz[b * 2 + 0];
        const float sh = osz[b * 2 + 1];
        const float* bx = boxes + ((size_t)(b * Qn + q)) * 4;
        float cx = bx[0], cy = bx[1], w = bx[2], h = bx[3];
        float* ob = out + OFF_BOXES + ((size_t)(b * Kn + tid)) * 4;
        ob[0] = (cx - 0.5f * w) * sw;
        ob[1] = (cy - 0.5f * h) * sh;
        ob[2] = (cx + 0.5f * w) * sw;
        ob[3] = (cy + 0.5f * h) * sh;

        qidx_ws[b * Kn + tid] = q;
    }
}

// ---------------------------------------------------------------------------
// Kernel B v5: period-5 in BOTH axes. Lane owns 20 consecutive output cols
// (= 4 groups of 5, sharing a 10-source-col window loaded as 2xb128 + 2xb32)
// and 10 output rows (2 groups of 5, advancing 2 source rows per group).
// All weights are literal constants {0.3,0.9,0.5,0.1,0.7}; borders handled by
// index clamping (sign-preserving, so the >0 threshold is unaffected).
// Per source row: 4 load instrs -> 20 h-values; per output row: 20 px =
// 2 VALU each + 5 float4 NT stores. No LDS, no barriers.
// ---------------------------------------------------------------------------
__global__ __launch_bounds__(256) void resize_kernel(
    const float* __restrict__ masks,    // [B,Q,128,128]
    const int* __restrict__ qidx_ws,    // [B,K]
    float* __restrict__ out)
{
    const int blk = blockIdx.x;
    const int bk  = blk >> 1;          // b*K + k
    const int hh  = blk & 1;           // 160-row half
    const int tid = threadIdx.x;
    const int b   = bk / Kn;
    const int q   = qidx_ws[bk];
    const int c   = tid & 15;          // col slab: out cols 20c..20c+19
    const int s   = tid >> 4;          // row slab: 10 rows

    const float* M = masks + ((size_t)(b * Qn + q)) * (MHs * MWs);
    const int colm1 = max(8 * c - 1, 0);
    const int colp8 = min(8 * c + 8, MWs - 1);

    float hA[20], hB[20], hC[20], hD[20];

    auto hrow = [&](float* hv, int r) {
        const float* row = M + r * MWs;
        vf4 u0 = *(const vf4*)(row + 8 * c);
        vf4 u1 = *(const vf4*)(row + 8 * c + 4);
        float a[10];
        a[0] = row[colm1];
        a[1] = u0[0]; a[2] = u0[1]; a[3] = u0[2]; a[4] = u0[3];
        a[5] = u1[0]; a[6] = u1[1]; a[7] = u1[2]; a[8] = u1[3];
        a[9] = row[colp8];
        #pragma unroll
        for (int u = 0; u < 4; ++u) {
            hv[5*u+0] = 0.3f * a[2*u]   + 0.7f * a[2*u+1];
            hv[5*u+1] = 0.9f * a[2*u+1] + 0.1f * a[2*u+2];
            hv[5*u+2] = 0.5f * a[2*u+1] + 0.5f * a[2*u+2];
            hv[5*u+3] = 0.1f * a[2*u+1] + 0.9f * a[2*u+2];
            hv[5*u+4] = 0.7f * a[2*u+2] + 0.3f * a[2*u+3];
        }
    };

    float* outm = out + OFF_MASKS + (size_t)bk * (THs * TWs);
    auto emit5 = [&](int row, float wA, const float* pA, float wB, const float* pB) {
        float* rp = outm + (size_t)row * TWs + 20 * c;
        #pragma unroll
        for (int v = 0; v < 5; ++v) {
            vf4 o;
            #pragma unroll
            for (int t = 0; t < 4; ++t) {
                float val = fmaf(wA, pA[4*v+t], wB * pB[4*v+t]);
                o[t] = (val > 0.0f) ? 1.0f : 0.0f;
            }
            __builtin_nontemporal_store(o, (vf4*)(rp + 4 * v));
        }
    };

    const int Mb = 32 * hh + 2 * s;
    const int Y0 = 160 * hh + 10 * s;
    hrow(hA, max(2 * Mb - 1, 0));
    hrow(hB, 2 * Mb);
    #pragma unroll
    for (int g = 0; g < 2; ++g) {
        const int Mg = Mb + g;
        hrow(hC, 2 * Mg + 1);
        hrow(hD, min(2 * Mg + 2, MHs - 1));
        const int Y = Y0 + 5 * g;
        emit5(Y + 0, 0.3f, hA, 0.7f, hB);
        emit5(Y + 1, 0.9f, hB, 0.1f, hC);
        emit5(Y + 2, 0.5f, hB, 0.5f, hC);
        emit5(Y + 3, 0.1f, hB, 0.9f, hC);
        emit5(Y + 4, 0.7f, hC, 0.3f, hD);
        #pragma unroll
        for (int i = 0; i < 20; ++i) { hA[i] = hC[i]; hB[i] = hD[i]; }
    }
}

// ---------------------------------------------------------------------------
extern "C" void kernel_launch(void* const* d_in, const int* in_sizes, int n_in,
                              void* d_out, int out_size, void* d_ws, size_t ws_size,
                              hipStream_t stream) {
    const float* logits = (const float*)d_in[0];   // [B,Q,C]
    const float* boxes  = (const float*)d_in[1];   // [B,Q,4]
    const float* masks  = (const float*)d_in[2];   // [B,Q,128,128]
    const float* osz    = (const float*)d_in[3];   // [B,2]
    // d_in[4]/d_in[5] = target_h/target_w (constant 320, baked in)

    float* out = (float*)d_out;
    int* qidx  = (int*)d_ws;                       // B*K ints

    topk_kernel<<<Bq, TPB, 0, stream>>>(logits, boxes, osz, out, qidx);
    resize_kernel<<<Bq * Kn * 2, 256, 0, stream>>>(masks, qidx, out);
}

// Round 6
// 331.359 us; speedup vs baseline: 2.4188x; 2.4188x over previous
//
#include <hip/hip_runtime.h>
#include <stdint.h>

// Problem constants (static shapes from the reference)
constexpr int Bq = 2;
constexpr int Qn = 300;
constexpr int Cn = 80;
constexpr int Kn = 300;
constexpr int NFLAT = Qn * Cn;   // 24000
constexpr int MHs = 128;
constexpr int MWs = 128;
constexpr int THs = 320;
constexpr int TWs = 320;

// Output layout (flat concatenation in reference return order, all as float)
constexpr int OFF_SCORES = 0;                         // [B,K]     600
constexpr int OFF_LABELS = Bq * Kn;                   // [B,K]     600
constexpr int OFF_BOXES  = 2 * Bq * Kn;               // [B,K,4]   2400
constexpr int OFF_MASKS  = 2 * Bq * Kn + Bq * Kn * 4; // [B,K,320,320]

constexpr int TPB = 1024;
constexpr int EPT = (NFLAT + TPB - 1) / TPB;          // 24 elements/thread

typedef float vf4  __attribute__((ext_vector_type(4)));              // 16B-aligned
typedef float uvf4 __attribute__((ext_vector_type(4), aligned(4)));  // align-4 load

// ---------------------------------------------------------------------------
// Kernel A v5: per-batch top-K with NO histogram (float-bit exponent
// compression made LDS histogram atomics serialize — the ~64us lesson of
// rounds 2-5). Keys (sigmoid bits, all >0, order-isomorphic) stay in VGPRs;
// threshold found by bisection on the 32-bit key: count(key>mid) via register
// compares + wave shuffle-reduce + 16 LDS atomics per iter (~12-15 iters,
// early exit when count<=768). Candidates collected once, ranked by count
// (unique 64-bit keys (bits<<32)|~idx  => exact jax.lax.top_k order).
// ---------------------------------------------------------------------------
__global__ __launch_bounds__(TPB) void topk_kernel(
    const float* __restrict__ logits,   // [B,Q,C]
    const float* __restrict__ boxes,    // [B,Q,4] cxcywh
    const float* __restrict__ osz,      // [B,2] (w,h)
    float* __restrict__ out,
    int* __restrict__ qidx_ws)          // [B,K]
{
    const int b   = blockIdx.x;
    const int tid = threadIdx.x;
    const float* lg = logits + (size_t)b * NFLAT;

    uint32_t key[EPT];
    #pragma unroll
    for (int j = 0; j < EPT; ++j) {
        int idx = j * TPB + tid;
        bool valid = (idx < NFLAT);
        float x = valid ? lg[idx] : 0.0f;
        float s = 1.0f / (1.0f + expf(-x));   // keep formula: matched ref rounds 1-5
        key[j] = valid ? __float_as_uint(s) : 0u;
    }

    __shared__ uint32_t sh_lo, sh_hi;
    __shared__ int sh_cnt, sh_done;
    __shared__ unsigned long long sk[1024];

    if (tid == 0) { sh_lo = 0u; sh_hi = 0xFFFFFFFFu; sh_cnt = 0; sh_done = 0; }
    __syncthreads();

    // Bisection: invariant count(key > sh_lo) >= K > count(key > sh_hi)
    for (int it = 0; it < 32; ++it) {
        if (sh_done) break;
        uint32_t lo = sh_lo, hi = sh_hi;
        if (hi - lo <= 1) break;
        uint32_t mid = lo + ((hi - lo) >> 1);
        int c = 0;
        #pragma unroll
        for (int j = 0; j < EPT; ++j) c += (key[j] > mid) ? 1 : 0;
        for (int off = 32; off > 0; off >>= 1) c += __shfl_down(c, off);
        if ((tid & 63) == 0 && c) atomicAdd(&sh_cnt, c);
        __syncthreads();
        if (tid == 0) {
            int total = sh_cnt;
            sh_cnt = 0;
            if (total >= Kn) { sh_lo = mid; if (total <= 768) sh_done = 1; }
            else             { sh_hi = mid; }
        }
        __syncthreads();
    }

    // Collect candidates: key > T  (strictly; count >= K guaranteed)
    const uint32_t T = sh_lo;
    #pragma unroll
    for (int j = 0; j < EPT; ++j) {
        int idx = j * TPB + tid;
        if (idx < NFLAT && key[j] > T) {
            int p = atomicAdd(&sh_cnt, 1);
            if (p < 1024)
                sk[p] = ((unsigned long long)key[j] << 32)
                      | (unsigned long long)(0xFFFFFFFFu - (uint32_t)idx);
        }
    }
    __syncthreads();

    // Rank by count (unique keys => ranks are a permutation; LDS broadcast)
    const int n = min(sh_cnt, 1024);
    if (tid < n) {
        unsigned long long my = sk[tid];
        int rank = 0;
        for (int i = 0; i < n; ++i) rank += (sk[i] > my) ? 1 : 0;
        if (rank < Kn) {
            uint32_t idx = 0xFFFFFFFFu - (uint32_t)(my & 0xFFFFFFFFull);
            float score  = __uint_as_float((uint32_t)(my >> 32));
            int label = (int)(idx % (uint32_t)Cn);
            int q     = (int)(idx / (uint32_t)Cn);

            out[OFF_SCORES + b * Kn + rank] = score;
            out[OFF_LABELS + b * Kn + rank] = (float)label;

            const float sw = osz[b * 2 + 0];
            const float sh = osz[b * 2 + 1];
            const float* bx = boxes + ((size_t)(b * Qn + q)) * 4;
            float cx = bx[0], cy = bx[1], w = bx[2], h = bx[3];
            float* ob = out + OFF_BOXES + ((size_t)(b * Kn + rank)) * 4;
            ob[0] = (cx - 0.5f * w) * sw;
            ob[1] = (cy - 0.5f * h) * sh;
            ob[2] = (cx + 0.5f * w) * sw;
            ob[3] = (cy + 0.5f * h) * sh;

            qidx_ws[b * Kn + rank] = q;
        }
    }
}

// ---------------------------------------------------------------------------
// Kernel B v6: v3's PROVEN store layout (lane = 4 consecutive output cols;
// wave stores are contiguous 64B-aligned runs -> zero write amplification)
// combined with cheap loads: all 8 x-taps for a lane's 4 px fall in a 4-wide
// source window (span<=3, proven), loaded as ONE align-4 dwordx4; x-weights
// are a per-lane zero-padded 4x4 dot table in registers (no dynamic index).
// y uses the period-5 rotation: 2 new source rows per 5 output rows.
// Borders by index clamp (sign-preserving => threshold unaffected).
// ---------------------------------------------------------------------------
__global__ __launch_bounds__(320) void resize_kernel(
    const float* __restrict__ masks,    // [B,Q,128,128]
    const int* __restrict__ qidx_ws,    // [B,K]
    float* __restrict__ out)
{
    const int blk = blockIdx.x;
    const int bk  = blk >> 2;          // b*K + k
    const int s   = blk & 3;           // 80-row chunk
    const int tid = threadIdx.x;
    const int b   = bk / Kn;
    const int q   = qidx_ws[bk];
    const int c   = tid % 80;          // out cols 4c..4c+3
    const int rs  = tid / 80;          // 20-row slab within chunk

    const float* M = masks + ((size_t)(b * Qn + q)) * (MHs * MWs);

    // ---- x setup: source window base s0 and 4x4 zero-padded weight table
    int s0;
    {
        float sx0 = fmaf(0.4f, (float)(4 * c), -0.3f);
        int i0 = (int)floorf(sx0);
        s0 = min(max(i0, 0), MWs - 4);   // [0,124]
    }
    float W[4][4];
    #pragma unroll
    for (int t = 0; t < 4; ++t) {
        int ox = 4 * c + t;
        float sx = fmaf(0.4f, (float)ox, -0.3f);
        int ix0 = (int)floorf(sx);
        float fr = sx - (float)ix0;
        int ca = max(ix0, 0);
        int cb = min(ix0 + 1, MWs - 1);
        float wa = 1.0f - fr, wb = fr;
        #pragma unroll
        for (int j = 0; j < 4; ++j) {
            float w = 0.0f;
            if (s0 + j == ca) w += wa;
            if (s0 + j == cb) w += wb;
            W[t][j] = w;
        }
    }

    auto hrow = [&](float* hv, int r) {
        uvf4 a = *(const uvf4*)(M + r * MWs + s0);
        #pragma unroll
        for (int t = 0; t < 4; ++t)
            hv[t] = fmaf(W[t][0], a[0],
                    fmaf(W[t][1], a[1],
                    fmaf(W[t][2], a[2], W[t][3] * a[3])));
    };

    float* outm = out + OFF_MASKS + (size_t)bk * (THs * TWs);
    auto emit = [&](int row, float wA, const float* pA, float wB, const float* pB) {
        vf4 o;
        #pragma unroll
        for (int t = 0; t < 4; ++t) {
            float v = fmaf(wA, pA[t], wB * pB[t]);
            o[t] = (v > 0.0f) ? 1.0f : 0.0f;
        }
        __builtin_nontemporal_store(o, (vf4*)(outm + (size_t)row * TWs + 4 * c));
    };

    const int Y0 = 80 * s + 20 * rs;   // first output row of this lane
    const int M0 = Y0 / 5;             // 16s + 4rs

    float hA[4], hB[4], hC[4], hD[4];
    hrow(hC, max(2 * M0 - 1, 0));
    hrow(hD, 2 * M0);

    #pragma unroll
    for (int g = 0; g < 4; ++g) {
        #pragma unroll
        for (int t = 0; t < 4; ++t) { hA[t] = hC[t]; hB[t] = hD[t]; }
        const int Mg = M0 + g;
        hrow(hC, 2 * Mg + 1);
        hrow(hD, min(2 * Mg + 2, MHs - 1));

        const int Y = Y0 + 5 * g;
        emit(Y + 0, 0.3f, hA, 0.7f, hB);   // phase 0: h[2m-1], h[2m]
        emit(Y + 1, 0.9f, hB, 0.1f, hC);   // phase 1: h[2m],  h[2m+1]
        emit(Y + 2, 0.5f, hB, 0.5f, hC);   // phase 2
        emit(Y + 3, 0.1f, hB, 0.9f, hC);   // phase 3
        emit(Y + 4, 0.7f, hC, 0.3f, hD);   // phase 4: h[2m+1], h[2m+2]
    }
}

// ---------------------------------------------------------------------------
extern "C" void kernel_launch(void* const* d_in, const int* in_sizes, int n_in,
                              void* d_out, int out_size, void* d_ws, size_t ws_size,
                              hipStream_t stream) {
    const float* logits = (const float*)d_in[0];   // [B,Q,C]
    const float* boxes  = (const float*)d_in[1];   // [B,Q,4]
    const float* masks  = (const float*)d_in[2];   // [B,Q,128,128]
    const float* osz    = (const float*)d_in[3];   // [B,2]
    // d_in[4]/d_in[5] = target_h/target_w (constant 320, baked in)

    float* out = (float*)d_out;
    int* qidx  = (int*)d_ws;                       // B*K ints

    topk_kernel<<<Bq, TPB, 0, stream>>>(logits, boxes, osz, out, qidx);
    resize_kernel<<<Bq * Kn * 4, 320, 0, stream>>>(masks, qidx, out);
}